// Round 1
// baseline (109.647 us; speedup 1.0000x reference)
//
#include <hip/hip_runtime.h>

// Phase vocoder with fixed rate followed by abs() of the complex result.
// abs(mag * e^{i phi}) == mag, so only the magnitude interpolation survives:
//   out[b,f,t] = alpha * |spec[b,f,idx+1]| + (1-alpha) * |spec[b,f,idx]|
// with tf = t*1.2f (f32), idx = trunc(tf), alpha = tf - idx, and the
// torchaudio-style zero pad at the time end (idx+1 == T reads 0).

#define RATE_F 1.2f

__global__ __launch_bounds__(256) void pv_mag_kernel(
    const float* __restrict__ re, const float* __restrict__ im,
    float* __restrict__ out, int total, int T_out, int T) {
    int stride = gridDim.x * blockDim.x;
    for (int i = blockIdx.x * blockDim.x + threadIdx.x; i < total; i += stride) {
        int t   = i % T_out;
        int row = i / T_out;
        float tf  = (float)t * RATE_F;      // matches jnp.arange(0,T,1.2,f32)
        int   idx = (int)tf;                // trunc == floor (tf >= 0)
        float alpha = tf - (float)idx;      // == tf % 1.0 for tf >= 0

        const float* __restrict__ rrow = re + (size_t)row * (size_t)T;
        const float* __restrict__ irow = im + (size_t)row * (size_t)T;

        float r0 = rrow[idx];
        float i0 = irow[idx];
        float r1 = 0.0f, i1 = 0.0f;
        if (idx + 1 < T) {                  // pad-by-2 => index T reads zero
            r1 = rrow[idx + 1];
            i1 = irow[idx + 1];
        }
        float n0 = sqrtf(r0 * r0 + i0 * i0);
        float n1 = sqrtf(r1 * r1 + i1 * i1);
        out[i] = alpha * n1 + (1.0f - alpha) * n0;
    }
}

extern "C" void kernel_launch(void* const* d_in, const int* in_sizes, int n_in,
                              void* d_out, int out_size, void* d_ws, size_t ws_size,
                              hipStream_t stream) {
    const float* re = (const float*)d_in[0];
    const float* im = (const float*)d_in[1];
    float* out = (float*)d_out;

    const int T  = 2048;                       // input time frames
    const int BF = in_sizes[0] / T;            // 16 * 1025 rows
    const int T_out = out_size / BF;           // 1707

    const int block = 256;
    int grid = (out_size + block - 1) / block;
    if (grid > 2048) grid = 2048;              // grid-stride, ~8 blocks/CU

    pv_mag_kernel<<<grid, block, 0, stream>>>(re, im, out, out_size, T_out, T);
}

// Round 2
// 72.834 us; speedup vs baseline: 1.5054x; 1.5054x over previous
//
#include <hip/hip_runtime.h>

// Phase vocoder (fixed rate 1.2) + abs() of the complex reconstruction.
// abs(mag * e^{i phi}) == mag, so only magnitude interpolation survives:
//   out[b,f,t] = alpha * n[idx+1] + (1-alpha) * n[idx],  n[k] = |spec[b,f,k]|
// tf = t*1.2f (f32), idx = trunc(tf), alpha = tf - idx; n[2048] = 0 (zero pad).
//
// One block per (b,f) row: coalesced float4 loads of re/im, norms staged in
// LDS once per input frame, coalesced dword stores of the output row.

#define RATE_F 1.2f
#define T_IN 2048

__global__ __launch_bounds__(256) void pv_row_kernel(
    const float* __restrict__ re, const float* __restrict__ im,
    float* __restrict__ out, int T_out) {
    __shared__ float n[T_IN + 8];   // +8: idx+1 can reach T_IN (reads zero pad)

    const int row = blockIdx.x;
    const int j   = threadIdx.x;

    const float4* __restrict__ re4 =
        (const float4*)(re + (size_t)row * T_IN);
    const float4* __restrict__ im4 =
        (const float4*)(im + (size_t)row * T_IN);

    // 2048 floats / 4 = 512 float4 per tensor; 256 threads -> 2 each.
#pragma unroll
    for (int k = 0; k < 2; ++k) {
        int v = k * 256 + j;            // float4 index within the row
        float4 r = re4[v];
        float4 q = im4[v];
        float4 m;
        m.x = sqrtf(r.x * r.x + q.x * q.x);
        m.y = sqrtf(r.y * r.y + q.y * q.y);
        m.z = sqrtf(r.z * r.z + q.z * q.z);
        m.w = sqrtf(r.w * r.w + q.w * q.w);
        *(float4*)&n[v * 4] = m;
    }
    if (j < 8) n[T_IN + j] = 0.0f;      // zero pad for idx+1 == T_IN
    __syncthreads();

    float* __restrict__ orow = out + (size_t)row * (size_t)T_out;
    for (int t = j; t < T_out; t += 256) {
        float tf  = (float)t * RATE_F;  // matches jnp.arange(0, T, 1.2, f32)
        int   idx = (int)tf;
        float a   = tf - (float)idx;
        float n0  = n[idx];
        float n1  = n[idx + 1];
        orow[t] = a * n1 + (1.0f - a) * n0;
    }
}

extern "C" void kernel_launch(void* const* d_in, const int* in_sizes, int n_in,
                              void* d_out, int out_size, void* d_ws, size_t ws_size,
                              hipStream_t stream) {
    const float* re = (const float*)d_in[0];
    const float* im = (const float*)d_in[1];
    float* out = (float*)d_out;

    const int BF    = in_sizes[0] / T_IN;   // 16 * 1025 rows
    const int T_out = out_size / BF;        // 1707

    pv_row_kernel<<<BF, 256, 0, stream>>>(re, im, out, T_out);
}

// Round 4
// 59.971 us; speedup vs baseline: 1.8283x; 1.2145x over previous
//
#include <hip/hip_runtime.h>

// Phase vocoder (fixed rate 1.2) + abs() of complex result == magnitude interp:
//   out[row,t] = a * n[idx+1] + (1-a) * n[idx],  n[k] = |spec[row,k]|, n[2048]=0
//   tf = (float)t * 1.2f, idx = trunc(tf), a = tf - idx.
// One block per row. Stage norms in LDS via coalesced float4 loads; emit the
// output row as float4 nontemporal stores (write-once data must not evict the
// input working set from L2/L3).

#define RATE_F 1.2f
#define T_IN 2048

typedef float vf4 __attribute__((ext_vector_type(4)));  // native vec for nt store

__global__ __launch_bounds__(256) void pv_row_kernel(
    const float* __restrict__ re, const float* __restrict__ im,
    float* __restrict__ out, int T_out) {
    __shared__ float n[T_IN + 8];   // +8: idx+1 can reach T_IN (zero pad)

    const int row = blockIdx.x;
    const int j   = threadIdx.x;

    const float4* __restrict__ re4 = (const float4*)(re + (size_t)row * T_IN);
    const float4* __restrict__ im4 = (const float4*)(im + (size_t)row * T_IN);

    // 2048 floats / 4 = 512 float4 per tensor; 256 threads -> 2 each.
#pragma unroll
    for (int k = 0; k < 2; ++k) {
        int v = k * 256 + j;
        float4 r = re4[v];
        float4 q = im4[v];
        float4 m;
        m.x = sqrtf(r.x * r.x + q.x * q.x);
        m.y = sqrtf(r.y * r.y + q.y * q.y);
        m.z = sqrtf(r.z * r.z + q.z * q.z);
        m.w = sqrtf(r.w * r.w + q.w * q.w);
        *(float4*)&n[v * 4] = m;
    }
    if (j < 8) n[T_IN + j] = 0.0f;
    __syncthreads();

    float* __restrict__ orow = out + (size_t)row * (size_t)T_out;
    const int nvec = T_out >> 2;            // 426 full float4 stores
#pragma unroll
    for (int it = 0; it < 2; ++it) {
        int v = it * 256 + j;
        if (v < nvec) {
            vf4 o;
            {
                float tf = (float)(4 * v + 0) * RATE_F;
                int idx = (int)tf; float a = tf - (float)idx;
                o.x = a * n[idx + 1] + (1.0f - a) * n[idx];
            }
            {
                float tf = (float)(4 * v + 1) * RATE_F;
                int idx = (int)tf; float a = tf - (float)idx;
                o.y = a * n[idx + 1] + (1.0f - a) * n[idx];
            }
            {
                float tf = (float)(4 * v + 2) * RATE_F;
                int idx = (int)tf; float a = tf - (float)idx;
                o.z = a * n[idx + 1] + (1.0f - a) * n[idx];
            }
            {
                float tf = (float)(4 * v + 3) * RATE_F;
                int idx = (int)tf; float a = tf - (float)idx;
                o.w = a * n[idx + 1] + (1.0f - a) * n[idx];
            }
            __builtin_nontemporal_store(o, (vf4*)&orow[4 * v]);
        } else if (v == nvec) {
            // tail: T_out % 4 elements (3 for T_out = 1707)
            for (int t = 4 * nvec; t < T_out; ++t) {
                float tf = (float)t * RATE_F;
                int idx = (int)tf; float a = tf - (float)idx;
                float val = a * n[idx + 1] + (1.0f - a) * n[idx];
                __builtin_nontemporal_store(val, &orow[t]);
            }
        }
    }
}

extern "C" void kernel_launch(void* const* d_in, const int* in_sizes, int n_in,
                              void* d_out, int out_size, void* d_ws, size_t ws_size,
                              hipStream_t stream) {
    const float* re = (const float*)d_in[0];
    const float* im = (const float*)d_in[1];
    float* out = (float*)d_out;

    const int BF    = in_sizes[0] / T_IN;   // 16 * 1025 rows
    const int T_out = out_size / BF;        // 1707

    pv_row_kernel<<<BF, 256, 0, stream>>>(re, im, out, T_out);
}